// Round 1
// baseline (508.953 us; speedup 1.0000x reference)
//
#include <hip/hip_runtime.h>

// ---------------------------------------------------------------- types
typedef _Float16 f16;
typedef _Float16 f16x8 __attribute__((ext_vector_type(8)));
typedef _Float16 f16x4 __attribute__((ext_vector_type(4)));
typedef float f32x4 __attribute__((ext_vector_type(4)));

#define DEVI __device__ __forceinline__

DEVI f32x4 mfma16(f16x8 a, f16x8 b, f32x4 c) {
    return __builtin_amdgcn_mfma_f32_16x16x32_f16(a, b, c, 0, 0, 0);
}

DEVI void gload_lds16(const void* g, void* l) {
    __builtin_amdgcn_global_load_lds(
        (const __attribute__((address_space(1))) void*)g,
        (__attribute__((address_space(3))) void*)l,
        16, 0, 0);
}

DEVI float gelu_exact(float v) {
    return 0.5f * v * (1.0f + erff(v * 0.70710678118654752f));
}

// ---------------------------------------------------------------- prep kernels
__global__ void cast_f16_kernel(const float* __restrict__ in, f16* __restrict__ out, int n4) {
    int i = blockIdx.x * 256 + threadIdx.x;
    if (i >= n4) return;
    float4 v = ((const float4*)in)[i];
    f16x4 o = {(f16)v.x, (f16)v.y, (f16)v.z, (f16)v.w};
    ((f16x4*)out)[i] = o;
}

// W: Kd x Nd fp32 row-major  ->  Wt: Nd x Kd f16 row-major
__global__ __launch_bounds__(256) void transpose_cast_kernel(
    const float* __restrict__ W, f16* __restrict__ Wt, int Kd, int Nd) {
    __shared__ float tile[32][33];
    const int n0 = blockIdx.x * 32, k0 = blockIdx.y * 32;
    const int tx = threadIdx.x & 31, ty = threadIdx.x >> 5;
#pragma unroll
    for (int i = ty; i < 32; i += 8)
        tile[i][tx] = W[(size_t)(k0 + i) * Nd + n0 + tx];
    __syncthreads();
#pragma unroll
    for (int i = ty; i < 32; i += 8)
        Wt[(size_t)(n0 + i) * Kd + k0 + tx] = (f16)tile[tx][i];
}

__global__ void rope_table_kernel(float2* __restrict__ cs) {
    int idx = blockIdx.x * 256 + threadIdx.x;   // L*32 = 65536
    int l = idx >> 5, i = idx & 31;
    float inv = expf(-((float)(2 * i) / 64.0f) * logf(10000.0f));
    float fr = (float)l * inv;
    float sn, cn;
    sincosf(fr, &sn, &cn);
    cs[idx] = make_float2(cn, sn);
}

// ---------------------------------------------------------------- GEMM (A: MxK f16, Bt: NxK f16)
enum { EPI_NONE = 0, EPI_GELU = 1 };

template <int EPI, typename OutT>
__global__ __launch_bounds__(256) void gemm_bt(
    const f16* __restrict__ A, const f16* __restrict__ Bt,
    const float* __restrict__ bias, OutT* __restrict__ C,
    int M, int N, int K) {
    constexpr int BM = 128, BN = 128, BK = 64;
    __shared__ f16 lds_a[BM * BK];
    __shared__ f16 lds_b[BN * BK];

    const int nbn = N / BN;
    const int bm = blockIdx.x / nbn, bn = blockIdx.x % nbn;
    const int tid = threadIdx.x;
    const int wave = tid >> 6, lane = tid & 63;
    const int lo = lane & 15, hi = lane >> 4;
    const int wr = (wave >> 1) * 64, wc = (wave & 1) * 64;

    const f16* Ag = A + (size_t)bm * BM * K;
    const f16* Bg = Bt + (size_t)bn * BN * K;

    f32x4 acc[4][4] = {};

    for (int k0 = 0; k0 < K; k0 += BK) {
        __syncthreads();
        // stage A and B tiles: 1024 16B-chunks each; physical chunk pc holds
        // logical (row=pc>>3, c8=(pc&7)^(row&7))  (XOR swizzle via pre-swizzled
        // global source; LDS stays linear for global_load_lds)
#pragma unroll
        for (int c = 0; c < 4; ++c) {
            int pc = wave * 256 + c * 64 + lane;
            int r = pc >> 3;
            int col = ((pc & 7) ^ (r & 7)) * 8;
            gload_lds16(Ag + (size_t)r * K + k0 + col, &lds_a[(wave * 256 + c * 64) * 8]);
            gload_lds16(Bg + (size_t)r * K + k0 + col, &lds_b[(wave * 256 + c * 64) * 8]);
        }
        __syncthreads();
#pragma unroll
        for (int kk = 0; kk < 2; ++kk) {
            f16x8 af[4], bf[4];
            const int slot = (kk * 4 + hi) ^ (lo & 7);
#pragma unroll
            for (int m = 0; m < 4; ++m)
                af[m] = *(const f16x8*)&lds_a[(wr + m * 16 + lo) * 64 + slot * 8];
#pragma unroll
            for (int n = 0; n < 4; ++n)
                bf[n] = *(const f16x8*)&lds_b[(wc + n * 16 + lo) * 64 + slot * 8];
#pragma unroll
            for (int m = 0; m < 4; ++m)
#pragma unroll
                for (int n = 0; n < 4; ++n)
                    acc[m][n] = mfma16(af[m], bf[n], acc[m][n]);
        }
    }
    // epilogue: D layout col=lane&15, row=(lane>>4)*4+reg
#pragma unroll
    for (int m = 0; m < 4; ++m)
#pragma unroll
        for (int n = 0; n < 4; ++n)
#pragma unroll
            for (int r = 0; r < 4; ++r) {
                int row = bm * BM + wr + m * 16 + hi * 4 + r;
                int col = bn * BN + wc + n * 16 + lo;
                float v = acc[m][n][r] + bias[col];
                if (EPI == EPI_GELU) v = gelu_exact(v);
                C[(size_t)row * N + col] = (OutT)v;
            }
}

// ---------------------------------------------------------------- RoPE + pack
// qkv: [B*L][3072] f16 -> Q,K: [B*H][L][64] f16 (Q scaled 0.125), Vt: [B*H][64][L]
__global__ __launch_bounds__(256) void rope_pack_kernel(
    const f16* __restrict__ qkv, const float2* __restrict__ cs,
    f16* __restrict__ Q, f16* __restrict__ Kf, f16* __restrict__ Vt) {
    constexpr int L = 2048;
    const int blk = blockIdx.x;             // B*H*(L/64) = 1024
    const int lt = blk & 31, h = (blk >> 5) & 15, b = blk >> 9;
    const int t = threadIdx.x, r = t >> 2, sub = t & 3;
    const int l = lt * 64 + r;
    const size_t base = (size_t)(b * L + l) * 3072 + h * 64 + sub * 8;

    f16x8 qlo = *(const f16x8*)&qkv[base];
    f16x8 qhi = *(const f16x8*)&qkv[base + 32];
    f16x8 klo = *(const f16x8*)&qkv[base + 1024];
    f16x8 khi = *(const f16x8*)&qkv[base + 1024 + 32];
    f16x8 vlo = *(const f16x8*)&qkv[base + 2048];
    f16x8 vhi = *(const f16x8*)&qkv[base + 2048 + 32];

    f16x8 qol, qoh, kol, koh;
#pragma unroll
    for (int j = 0; j < 8; ++j) {
        float2 c = cs[l * 32 + sub * 8 + j];
        float q1 = (float)qlo[j], q2 = (float)qhi[j];
        float k1 = (float)klo[j], k2 = (float)khi[j];
        qol[j] = (f16)((q1 * c.x - q2 * c.y) * 0.125f);
        qoh[j] = (f16)((q2 * c.x + q1 * c.y) * 0.125f);
        kol[j] = (f16)(k1 * c.x - k2 * c.y);
        koh[j] = (f16)(k2 * c.x + k1 * c.y);
    }
    const size_t qbase = (size_t)((b * 16 + h) * L + l) * 64 + sub * 8;
    *(f16x8*)&Q[qbase] = qol;
    *(f16x8*)&Q[qbase + 32] = qoh;
    *(f16x8*)&Kf[qbase] = kol;
    *(f16x8*)&Kf[qbase + 32] = koh;

    __shared__ f16 vt[64][72];              // 72: keep rows 16B-aligned
#pragma unroll
    for (int j = 0; j < 8; ++j) {
        vt[sub * 8 + j][r] = vlo[j];
        vt[sub * 8 + 32 + j][r] = vhi[j];
    }
    __syncthreads();
    const int d = t >> 2, seg = t & 3;
    const size_t vbase = (size_t)((b * 16 + h) * 64 + d) * L + lt * 64 + seg * 16;
    *(f16x8*)&Vt[vbase] = *(const f16x8*)&vt[d][seg * 16];
    *(f16x8*)&Vt[vbase + 8] = *(const f16x8*)&vt[d][seg * 16 + 8];
}

// ---------------------------------------------------------------- attention
// Q,K: [B*H][L][64] (Q pre-scaled), Vt: [B*H][64][L], Out: [B][L][H][64] f16
__global__ __launch_bounds__(256) void attn_fwd(
    const f16* __restrict__ Q, const f16* __restrict__ Kf,
    const f16* __restrict__ Vt, f16* __restrict__ Out) {
    constexpr int L = 2048, HD = 64, NH = 16;
    const int bh = blockIdx.x >> 5;
    const int qb = blockIdx.x & 31;
    const int wave = threadIdx.x >> 6, lane = threadIdx.x & 63;
    const int lo = lane & 15, hi = lane >> 4;
    const int q0 = qb * 64 + wave * 16;

    const f16* Qh = Q + (size_t)bh * L * HD;
    const f16* Kh = Kf + (size_t)bh * L * HD;
    const f16* Vh = Vt + (size_t)bh * HD * L;

    __shared__ f16 p_lds[4][16 * 64];       // per-wave P tile, XOR-swizzled

    f16x8 aq[2];
#pragma unroll
    for (int kk = 0; kk < 2; ++kk)
        aq[kk] = *(const f16x8*)&Qh[(size_t)(q0 + lo) * HD + kk * 32 + hi * 8];

    f32x4 oacc[4] = {};
    float m_run[4], l_run[4];
#pragma unroll
    for (int r = 0; r < 4; ++r) { m_run[r] = -1e30f; l_run[r] = 0.0f; }

    for (int kb = 0; kb < L / 64; ++kb) {
        const int key0 = kb * 64;
        // S = Q K^T  (D: row=q=(hi*4+r), col=key=nt*16+lo)
        f32x4 s[4];
#pragma unroll
        for (int nt = 0; nt < 4; ++nt) {
            f32x4 z = {};
#pragma unroll
            for (int kk = 0; kk < 2; ++kk) {
                f16x8 bk = *(const f16x8*)&Kh[(size_t)(key0 + nt * 16 + lo) * HD + kk * 32 + hi * 8];
                z = mfma16(aq[kk], bk, z);
            }
            s[nt] = z;
        }
        // online softmax (rows live on 16-lane lo-groups)
        float scale[4];
#pragma unroll
        for (int r = 0; r < 4; ++r) {
            float mx = fmaxf(fmaxf(s[0][r], s[1][r]), fmaxf(s[2][r], s[3][r]));
#pragma unroll
            for (int msk = 1; msk < 16; msk <<= 1)
                mx = fmaxf(mx, __shfl_xor(mx, msk));
            float mnew = fmaxf(m_run[r], mx);
            scale[r] = __expf(m_run[r] - mnew);
            m_run[r] = mnew;
        }
        float lsum[4] = {0.f, 0.f, 0.f, 0.f};
#pragma unroll
        for (int nt = 0; nt < 4; ++nt)
#pragma unroll
            for (int r = 0; r < 4; ++r) {
                float p = __expf(s[nt][r] - m_run[r]);
                s[nt][r] = p;
                lsum[r] += p;
            }
#pragma unroll
        for (int r = 0; r < 4; ++r) {
#pragma unroll
            for (int msk = 1; msk < 16; msk <<= 1)
                lsum[r] += __shfl_xor(lsum[r], msk);
            l_run[r] = l_run[r] * scale[r] + lsum[r];
        }
#pragma unroll
        for (int nt = 0; nt < 4; ++nt)
#pragma unroll
            for (int r = 0; r < 4; ++r)
                oacc[nt][r] *= scale[r];
        // P -> LDS (bf16-tile swizzle: slot ^= row&7)
#pragma unroll
        for (int nt = 0; nt < 4; ++nt)
#pragma unroll
            for (int r = 0; r < 4; ++r) {
                int prow = hi * 4 + r;
                int colb = (nt * 16 + lo) * 2;
                int slot = (colb >> 4) ^ (prow & 7);
                int off = prow * 128 + slot * 16 + (colb & 15);
                p_lds[wave][off >> 1] = (f16)s[nt][r];
            }
        __syncthreads();
        // O += P V  (A-frag row=lo, k=key; B-frag from Vt contiguous)
#pragma unroll
        for (int kk = 0; kk < 2; ++kk) {
            const int slot = (kk * 4 + hi) ^ (lo & 7);
            f16x8 pa = *(const f16x8*)&p_lds[wave][lo * 64 + slot * 8];
#pragma unroll
            for (int nt = 0; nt < 4; ++nt) {
                f16x8 vb = *(const f16x8*)&Vh[(size_t)(nt * 16 + lo) * L + key0 + kk * 32 + hi * 8];
                oacc[nt] = mfma16(pa, vb, oacc[nt]);
            }
        }
        __syncthreads();
    }
    const int b = bh >> 4, h = bh & 15;
#pragma unroll
    for (int nt = 0; nt < 4; ++nt)
#pragma unroll
        for (int r = 0; r < 4; ++r) {
            int l = q0 + hi * 4 + r;
            int d = nt * 16 + lo;
            Out[((size_t)(b * L + l) * NH + h) * HD + d] = (f16)(oacc[nt][r] / l_run[r]);
        }
}

// ---------------------------------------------------------------- residual + LayerNorm
template <bool WB>
__global__ __launch_bounds__(256) void ln_fused(
    const float* __restrict__ X, const float* __restrict__ Y,
    const float* __restrict__ g, const float* __restrict__ b,
    float* __restrict__ outF, f16* __restrict__ outH) {
    const int row = blockIdx.x, t = threadIdx.x;
    const float4 xv = ((const float4*)(X + (size_t)row * 1024))[t];
    const float4 yv = ((const float4*)(Y + (size_t)row * 1024))[t];
    float v0 = xv.x + yv.x, v1 = xv.y + yv.y, v2 = xv.z + yv.z, v3 = xv.w + yv.w;
    __shared__ float red[8];
    float s = v0 + v1 + v2 + v3;
#pragma unroll
    for (int m = 1; m < 64; m <<= 1) s += __shfl_xor(s, m);
    if ((t & 63) == 0) red[t >> 6] = s;
    __syncthreads();
    float mu = (red[0] + red[1] + red[2] + red[3]) * (1.0f / 1024.0f);
    float d0 = v0 - mu, d1 = v1 - mu, d2 = v2 - mu, d3 = v3 - mu;
    float q = d0 * d0 + d1 * d1 + d2 * d2 + d3 * d3;
#pragma unroll
    for (int m = 1; m < 64; m <<= 1) q += __shfl_xor(q, m);
    if ((t & 63) == 0) red[4 + (t >> 6)] = q;
    __syncthreads();
    float var = (red[4] + red[5] + red[6] + red[7]) * (1.0f / 1024.0f);
    float rs = rsqrtf(var + 1e-5f);
    const float4 gv = ((const float4*)g)[t];
    const float4 bv = ((const float4*)b)[t];
    float o0 = d0 * rs * gv.x + bv.x;
    float o1 = d1 * rs * gv.y + bv.y;
    float o2 = d2 * rs * gv.z + bv.z;
    float o3 = d3 * rs * gv.w + bv.w;
    float4 ov = {o0, o1, o2, o3};
    ((float4*)(outF + (size_t)row * 1024))[t] = ov;
    if constexpr (WB) {
        f16x4 oh = {(f16)o0, (f16)o1, (f16)o2, (f16)o3};
        ((f16x4*)(outH + (size_t)row * 1024))[t] = oh;
    }
}

// ---------------------------------------------------------------- launch
extern "C" void kernel_launch(void* const* d_in, const int* in_sizes, int n_in,
                              void* d_out, int out_size, void* d_ws, size_t ws_size,
                              hipStream_t stream) {
    const float* x      = (const float*)d_in[0];
    const float* qkv_w  = (const float*)d_in[1];
    const float* qkv_b  = (const float*)d_in[2];
    const float* out_w  = (const float*)d_in[3];
    const float* out_b  = (const float*)d_in[4];
    const float* ln1_g  = (const float*)d_in[5];
    const float* ln1_b  = (const float*)d_in[6];
    const float* ln2_g  = (const float*)d_in[7];
    const float* ln2_b  = (const float*)d_in[8];
    const float* ffn1_w = (const float*)d_in[9];
    const float* ffn1_b = (const float*)d_in[10];
    const float* ffn2_w = (const float*)d_in[11];
    const float* ffn2_b = (const float*)d_in[12];
    float* out = (float*)d_out;
    char* ws = (char*)d_ws;

    // ---- workspace layout (bytes), all 256-aligned sizes
    constexpr size_t SZ_XB      = 4096ull * 1024 * 2;   // x f16
    constexpr size_t SZ_QKV_WT  = 3072ull * 1024 * 2;
    constexpr size_t SZ_OUT_WT  = 1024ull * 1024 * 2;
    constexpr size_t SZ_FFN1_WT = 4096ull * 1024 * 2;
    constexpr size_t SZ_FFN2_WT = 1024ull * 4096 * 2;
    constexpr size_t SZ_CS      = 2048ull * 32 * 8;
    constexpr size_t SZ_X1F     = 4096ull * 1024 * 4;
    constexpr size_t SZ_X1H     = 4096ull * 1024 * 2;
    constexpr size_t SZ_FFN2O   = 4096ull * 1024 * 4;
    constexpr size_t SZ_QH      = 32ull * 2048 * 64 * 2;   // 8 MB each
    constexpr size_t SZ_REGB    = 4 * SZ_QH;               // Q,K,Vt,attn_out (reused by h)
    constexpr size_t SZ_REGC    = 4096ull * 3072 * 2;      // qkv f16 (reused by proj f32)

    size_t o = 0;
    auto take = [&](size_t sz) { size_t p = o; o += (sz + 255) & ~(size_t)255; return p; };
    const size_t O_XB      = take(SZ_XB);
    const size_t O_QKV_WT  = take(SZ_QKV_WT);
    const size_t O_OUT_WT  = take(SZ_OUT_WT);
    const size_t O_FFN1_WT = take(SZ_FFN1_WT);
    const size_t O_FFN2_WT = take(SZ_FFN2_WT);
    const size_t O_CS      = take(SZ_CS);
    const size_t O_X1F     = take(SZ_X1F);
    const size_t O_X1H     = take(SZ_X1H);
    const size_t O_FFN2O   = take(SZ_FFN2O);
    const size_t O_REGB    = take(SZ_REGB);
    const size_t O_REGC    = take(SZ_REGC);

    f16*    xb      = (f16*)(ws + O_XB);
    f16*    qkv_wt  = (f16*)(ws + O_QKV_WT);
    f16*    out_wt  = (f16*)(ws + O_OUT_WT);
    f16*    ffn1_wt = (f16*)(ws + O_FFN1_WT);
    f16*    ffn2_wt = (f16*)(ws + O_FFN2_WT);
    float2* cs      = (float2*)(ws + O_CS);
    float*  x1f     = (float*)(ws + O_X1F);
    f16*    x1h     = (f16*)(ws + O_X1H);
    float*  ffn2o   = (float*)(ws + O_FFN2O);
    f16*    Qb      = (f16*)(ws + O_REGB);
    f16*    Kb      = (f16*)(ws + O_REGB + SZ_QH);
    f16*    Vtb     = (f16*)(ws + O_REGB + 2 * SZ_QH);
    f16*    attn_o  = (f16*)(ws + O_REGB + 3 * SZ_QH);
    f16*    hbuf    = (f16*)(ws + O_REGB);          // reuse (32 MB)
    f16*    qkvo    = (f16*)(ws + O_REGC);
    float*  proj    = (float*)(ws + O_REGC);        // reuse (16 MB <= 24 MB)

    // ---- prep
    cast_f16_kernel<<<4096, 256, 0, stream>>>(x, xb, 4096 * 1024 / 4);
    transpose_cast_kernel<<<dim3(96, 32), 256, 0, stream>>>(qkv_w, qkv_wt, 1024, 3072);
    transpose_cast_kernel<<<dim3(32, 32), 256, 0, stream>>>(out_w, out_wt, 1024, 1024);
    transpose_cast_kernel<<<dim3(128, 32), 256, 0, stream>>>(ffn1_w, ffn1_wt, 1024, 4096);
    transpose_cast_kernel<<<dim3(32, 128), 256, 0, stream>>>(ffn2_w, ffn2_wt, 4096, 1024);
    rope_table_kernel<<<256, 256, 0, stream>>>(cs);

    // ---- layer
    gemm_bt<EPI_NONE, f16><<<32 * 24, 256, 0, stream>>>(xb, qkv_wt, qkv_b, qkvo, 4096, 3072, 1024);
    rope_pack_kernel<<<1024, 256, 0, stream>>>(qkvo, cs, Qb, Kb, Vtb);
    attn_fwd<<<1024, 256, 0, stream>>>(Qb, Kb, Vtb, attn_o);
    gemm_bt<EPI_NONE, float><<<32 * 8, 256, 0, stream>>>(attn_o, out_wt, out_b, proj, 4096, 1024, 1024);
    ln_fused<true><<<4096, 256, 0, stream>>>(x, proj, ln1_g, ln1_b, x1f, x1h);
    gemm_bt<EPI_GELU, f16><<<32 * 32, 256, 0, stream>>>(x1h, ffn1_wt, ffn1_b, hbuf, 4096, 4096, 1024);
    gemm_bt<EPI_NONE, float><<<32 * 8, 256, 0, stream>>>(hbuf, ffn2_wt, ffn2_b, ffn2o, 4096, 1024, 4096);
    ln_fused<false><<<4096, 256, 0, stream>>>(x1f, ffn2o, ln2_g, ln2_b, out, nullptr);
}

// Round 3
// 388.280 us; speedup vs baseline: 1.3108x; 1.3108x over previous
//
#include <hip/hip_runtime.h>

// ---------------------------------------------------------------- types
typedef _Float16 f16;
typedef _Float16 f16x8 __attribute__((ext_vector_type(8)));
typedef _Float16 f16x4 __attribute__((ext_vector_type(4)));
typedef _Float16 f16x2 __attribute__((ext_vector_type(2)));
typedef float f32x4 __attribute__((ext_vector_type(4)));
typedef float f32x16 __attribute__((ext_vector_type(16)));
typedef unsigned int u32;

#define DEVI __device__ __forceinline__

DEVI f32x4 mfma16(f16x8 a, f16x8 b, f32x4 c) {
    return __builtin_amdgcn_mfma_f32_16x16x32_f16(a, b, c, 0, 0, 0);
}
DEVI f32x16 mfma32(f16x8 a, f16x8 b, f32x16 c) {
    return __builtin_amdgcn_mfma_f32_32x32x16_f16(a, b, c, 0, 0, 0);
}

DEVI void gload_lds16(const void* g, void* l) {
    __builtin_amdgcn_global_load_lds(
        (const __attribute__((address_space(1))) void*)g,
        (__attribute__((address_space(3))) void*)l,
        16, 0, 0);
}

DEVI float gelu_exact(float v) {
    return 0.5f * v * (1.0f + erff(v * 0.70710678118654752f));
}

// ---------------------------------------------------------------- prep kernels
__global__ void cast_f16_kernel(const float* __restrict__ in, f16* __restrict__ out, int n4) {
    int i = blockIdx.x * 256 + threadIdx.x;
    if (i >= n4) return;
    float4 v = ((const float4*)in)[i];
    f16x4 o = {(f16)v.x, (f16)v.y, (f16)v.z, (f16)v.w};
    ((f16x4*)out)[i] = o;
}

// W: Kd x Nd fp32 row-major  ->  Wt: Nd x Kd f16 row-major
__global__ __launch_bounds__(256) void transpose_cast_kernel(
    const float* __restrict__ W, f16* __restrict__ Wt, int Kd, int Nd) {
    __shared__ float tile[32][33];
    const int n0 = blockIdx.x * 32, k0 = blockIdx.y * 32;
    const int tx = threadIdx.x & 31, ty = threadIdx.x >> 5;
#pragma unroll
    for (int i = ty; i < 32; i += 8)
        tile[i][tx] = W[(size_t)(k0 + i) * Nd + n0 + tx];
    __syncthreads();
#pragma unroll
    for (int i = ty; i < 32; i += 8)
        Wt[(size_t)(n0 + i) * Kd + k0 + tx] = (f16)tile[tx][i];
}

__global__ void rope_table_kernel(float2* __restrict__ cs) {
    int idx = blockIdx.x * 256 + threadIdx.x;   // L*32 = 65536
    int l = idx >> 5, i = idx & 31;
    float inv = expf(-((float)(2 * i) / 64.0f) * logf(10000.0f));
    float fr = (float)l * inv;
    float sn, cn;
    sincosf(fr, &sn, &cn);
    cs[idx] = make_float2(cn, sn);
}

// ---------------------------------------------------------------- GEMM (A: MxK f16, Bt: NxK f16)
enum { EPI_NONE = 0, EPI_GELU = 1 };

template <int EPI, typename OutT>
__global__ __launch_bounds__(256) void gemm_bt(
    const f16* __restrict__ A, const f16* __restrict__ Bt,
    const float* __restrict__ bias, OutT* __restrict__ C,
    int M, int N, int K) {
    constexpr int BM = 128, BN = 128, BK = 64;
    __shared__ f16 lds_a[BM * BK];
    __shared__ f16 lds_b[BN * BK];

    const int nbn = N / BN;
    const int bm = blockIdx.x / nbn, bn = blockIdx.x % nbn;
    const int tid = threadIdx.x;
    const int wave = tid >> 6, lane = tid & 63;
    const int lo = lane & 15, hi = lane >> 4;
    const int wr = (wave >> 1) * 64, wc = (wave & 1) * 64;

    const f16* Ag = A + (size_t)bm * BM * K;
    const f16* Bg = Bt + (size_t)bn * BN * K;

    f32x4 acc[4][4] = {};

    for (int k0 = 0; k0 < K; k0 += BK) {
        __syncthreads();
#pragma unroll
        for (int c = 0; c < 4; ++c) {
            int pc = wave * 256 + c * 64 + lane;
            int r = pc >> 3;
            int col = ((pc & 7) ^ (r & 7)) * 8;
            gload_lds16(Ag + (size_t)r * K + k0 + col, &lds_a[(wave * 256 + c * 64) * 8]);
            gload_lds16(Bg + (size_t)r * K + k0 + col, &lds_b[(wave * 256 + c * 64) * 8]);
        }
        __syncthreads();
#pragma unroll
        for (int kk = 0; kk < 2; ++kk) {
            f16x8 af[4], bf[4];
            const int slot = (kk * 4 + hi) ^ (lo & 7);
#pragma unroll
            for (int m = 0; m < 4; ++m)
                af[m] = *(const f16x8*)&lds_a[(wr + m * 16 + lo) * 64 + slot * 8];
#pragma unroll
            for (int n = 0; n < 4; ++n)
                bf[n] = *(const f16x8*)&lds_b[(wc + n * 16 + lo) * 64 + slot * 8];
#pragma unroll
            for (int m = 0; m < 4; ++m)
#pragma unroll
                for (int n = 0; n < 4; ++n)
                    acc[m][n] = mfma16(af[m], bf[n], acc[m][n]);
        }
    }
#pragma unroll
    for (int m = 0; m < 4; ++m)
#pragma unroll
        for (int n = 0; n < 4; ++n)
#pragma unroll
            for (int r = 0; r < 4; ++r) {
                int row = bm * BM + wr + m * 16 + hi * 4 + r;
                int col = bn * BN + wc + n * 16 + lo;
                float v = acc[m][n][r] + bias[col];
                if (EPI == EPI_GELU) v = gelu_exact(v);
                C[(size_t)row * N + col] = (OutT)v;
            }
}

// ---------------------------------------------------------------- RoPE + pack
// qkv: [B*L][3072] f16 -> Q,K: [B*H][L][64] f16 (Q scaled 0.125), Vt: [B*H][64][L]
__global__ __launch_bounds__(256) void rope_pack_kernel(
    const f16* __restrict__ qkv, const float2* __restrict__ cs,
    f16* __restrict__ Q, f16* __restrict__ Kf, f16* __restrict__ Vt) {
    constexpr int L = 2048;
    const int blk = blockIdx.x;             // B*H*(L/64) = 1024
    const int lt = blk & 31, h = (blk >> 5) & 15, b = blk >> 9;
    const int t = threadIdx.x, r = t >> 2, sub = t & 3;
    const int l = lt * 64 + r;
    const size_t base = (size_t)(b * L + l) * 3072 + h * 64 + sub * 8;

    f16x8 qlo = *(const f16x8*)&qkv[base];
    f16x8 qhi = *(const f16x8*)&qkv[base + 32];
    f16x8 klo = *(const f16x8*)&qkv[base + 1024];
    f16x8 khi = *(const f16x8*)&qkv[base + 1024 + 32];
    f16x8 vlo = *(const f16x8*)&qkv[base + 2048];
    f16x8 vhi = *(const f16x8*)&qkv[base + 2048 + 32];

    f16x8 qol, qoh, kol, koh;
#pragma unroll
    for (int j = 0; j < 8; ++j) {
        float2 c = cs[l * 32 + sub * 8 + j];
        float q1 = (float)qlo[j], q2 = (float)qhi[j];
        float k1 = (float)klo[j], k2 = (float)khi[j];
        qol[j] = (f16)((q1 * c.x - q2 * c.y) * 0.125f);
        qoh[j] = (f16)((q2 * c.x + q1 * c.y) * 0.125f);
        kol[j] = (f16)(k1 * c.x - k2 * c.y);
        koh[j] = (f16)(k2 * c.x + k1 * c.y);
    }
    const size_t qbase = (size_t)((b * 16 + h) * L + l) * 64 + sub * 8;
    *(f16x8*)&Q[qbase] = qol;
    *(f16x8*)&Q[qbase + 32] = qoh;
    *(f16x8*)&Kf[qbase] = kol;
    *(f16x8*)&Kf[qbase + 32] = koh;

    __shared__ f16 vt[64][72];
#pragma unroll
    for (int j = 0; j < 8; ++j) {
        vt[sub * 8 + j][r] = vlo[j];
        vt[sub * 8 + 32 + j][r] = vhi[j];
    }
    __syncthreads();
    const int d = t >> 2, seg = t & 3;
    const size_t vbase = (size_t)((b * 16 + h) * 64 + d) * L + lt * 64 + seg * 16;
    *(f16x8*)&Vt[vbase] = *(const f16x8*)&vt[d][seg * 16];
    *(f16x8*)&Vt[vbase + 8] = *(const f16x8*)&vt[d][seg * 16 + 8];
}

// ---------------------------------------------------------------- attention (swapped 32x32, in-register softmax)
// Q,K: [B*H][L][64] (Q pre-scaled), Vt: [B*H][64][L], Out: [B][L][H][64] f16
// 8 waves/block, each wave owns 32 q-rows; no barriers in the main loop.
__global__ __launch_bounds__(512) void attn_fwd(
    const f16* __restrict__ Q, const f16* __restrict__ Kf,
    const f16* __restrict__ Vt, f16* __restrict__ Out) {
    constexpr int L = 2048, HD = 64;
    const int bh = blockIdx.x >> 3;          // b*16+h
    const int qt8 = blockIdx.x & 7;
    const int wave = threadIdx.x >> 6, lane = threadIdx.x & 63;
    const int ln = lane & 31, hi2 = lane >> 5;
    const int q0 = (qt8 * 8 + wave) * 32;

    const f16* Qh = Q + (size_t)bh * L * HD;
    const f16* Kh = Kf + (size_t)bh * L * HD;
    const f16* Vh = Vt + (size_t)bh * HD * L;

    // Q B-fragments: B[k=d][n=q]; lane holds Q[q0+ln][dblk*16 + hi2*8 + j]
    f16x8 bq[4];
#pragma unroll
    for (int dblk = 0; dblk < 4; ++dblk)
        bq[dblk] = *(const f16x8*)&Qh[(size_t)(q0 + ln) * HD + dblk * 16 + hi2 * 8];

    f32x16 oacc0 = {}, oacc1 = {};
    float m_run = -1e30f, l_run = 0.0f;

    // preload K fragments for key0 = 0
    f16x8 ak[4];
#pragma unroll
    for (int dblk = 0; dblk < 4; ++dblk)
        ak[dblk] = *(const f16x8*)&Kh[(size_t)ln * HD + dblk * 16 + hi2 * 8];

    for (int key0 = 0; key0 < L; key0 += 32) {
        // S^T[key][q] = sum_d K[key][d] Q[q][d]   (Q carries the 1/8 scale)
        f32x16 st = {};
#pragma unroll
        for (int dblk = 0; dblk < 4; ++dblk)
            st = mfma32(ak[dblk], bq[dblk], st);

        // prefetch V (this block) and K (next block) — hides L2 latency under softmax
        f16x8 av00 = *(const f16x8*)&Vh[(size_t)ln * L + key0 + hi2 * 8];
        f16x8 av01 = *(const f16x8*)&Vh[(size_t)ln * L + key0 + 16 + hi2 * 8];
        f16x8 av10 = *(const f16x8*)&Vh[(size_t)(32 + ln) * L + key0 + hi2 * 8];
        f16x8 av11 = *(const f16x8*)&Vh[(size_t)(32 + ln) * L + key0 + 16 + hi2 * 8];
        if (key0 + 32 < L) {
#pragma unroll
            for (int dblk = 0; dblk < 4; ++dblk)
                ak[dblk] = *(const f16x8*)&Kh[(size_t)(key0 + 32 + ln) * HD + dblk * 16 + hi2 * 8];
        }

        // ---- in-register online softmax; lane holds 16 scores of q=ln, partner holds other 16
        float mx = st[0];
#pragma unroll
        for (int r = 1; r < 16; ++r) mx = fmaxf(mx, st[r]);
        mx = fmaxf(mx, __shfl_xor(mx, 32));

        if (__any(mx > m_run + 8.0f)) {      // defer-max: rescale only on real growth
            float mnew = fmaxf(m_run, mx);
            float sc = __expf(m_run - mnew);
            m_run = mnew;
            l_run *= sc;
#pragma unroll
            for (int r = 0; r < 16; ++r) { oacc0[r] *= sc; oacc1[r] *= sc; }
        }

        float p[16];
        float sum = 0.0f;
#pragma unroll
        for (int r = 0; r < 16; ++r) {
            p[r] = __expf(st[r] - m_run);
            sum += p[r];
        }
        sum += __shfl_xor(sum, 32);
        l_run += sum;

        // pack P to f16 pairs (reg-order; key=(r&3)+8*(r>>2)+4*hi2)
        u32 pk[8];
#pragma unroll
        for (int i = 0; i < 8; ++i) {
            f16x2 t;
            t[0] = (f16)p[2 * i];
            t[1] = (f16)p[2 * i + 1];
            pk[i] = __builtin_bit_cast(u32, t);
        }
        // redistribute halves: 4 exchanges build exact PV B-fragments
        u32 ex0 = __shfl_xor(hi2 ? pk[0] : pk[2], 32);
        u32 ex1 = __shfl_xor(hi2 ? pk[1] : pk[3], 32);
        u32 ex2 = __shfl_xor(hi2 ? pk[4] : pk[6], 32);
        u32 ex3 = __shfl_xor(hi2 ? pk[5] : pk[7], 32);
        union U8 { u32 w[4]; f16x8 v; };
        U8 ub0, ub1;
        ub0.w[0] = hi2 ? ex0 : pk[0];
        ub0.w[1] = hi2 ? ex1 : pk[1];
        ub0.w[2] = hi2 ? pk[2] : ex0;
        ub0.w[3] = hi2 ? pk[3] : ex1;
        ub1.w[0] = hi2 ? ex2 : pk[4];
        ub1.w[1] = hi2 ? ex3 : pk[5];
        ub1.w[2] = hi2 ? pk[6] : ex2;
        ub1.w[3] = hi2 ? pk[7] : ex3;

        // O^T[d][q] += V^T · P^T
        oacc0 = mfma32(av00, ub0.v, oacc0);
        oacc1 = mfma32(av10, ub0.v, oacc1);
        oacc0 = mfma32(av01, ub1.v, oacc0);
        oacc1 = mfma32(av11, ub1.v, oacc1);
    }

    // ---- epilogue: O^T -> LDS transpose -> coalesced [B][L][H*64] store
    __shared__ f16 obuf[8][32][80];          // 80: rows 160 B -> every f16x8 16B-aligned
    float rl = 1.0f / l_run;
#pragma unroll
    for (int r = 0; r < 16; ++r) {
        int d = (r & 3) + 8 * (r >> 2) + 4 * hi2;
        obuf[wave][ln][d] = (f16)(oacc0[r] * rl);
        obuf[wave][ln][32 + d] = (f16)(oacc1[r] * rl);
    }
    __syncthreads();
    // each lane stores 32 halves: full coverage of d = hf*32 .. hf*32+31
    const int qrow = lane >> 1, hf = lane & 1;
    const int b = bh >> 4, h = bh & 15;
    const size_t orow = ((size_t)(b * L + q0 + qrow) * 16 + h) * 64 + hf * 32;
    f16x8 o0 = *(const f16x8*)&obuf[wave][qrow][hf * 32];
    f16x8 o1 = *(const f16x8*)&obuf[wave][qrow][hf * 32 + 8];
    f16x8 o2 = *(const f16x8*)&obuf[wave][qrow][hf * 32 + 16];
    f16x8 o3 = *(const f16x8*)&obuf[wave][qrow][hf * 32 + 24];
    *(f16x8*)&Out[orow] = o0;
    *(f16x8*)&Out[orow + 8] = o1;
    *(f16x8*)&Out[orow + 16] = o2;
    *(f16x8*)&Out[orow + 24] = o3;
}

// ---------------------------------------------------------------- residual + LayerNorm
template <bool WB>
__global__ __launch_bounds__(256) void ln_fused(
    const float* __restrict__ X, const float* __restrict__ Y,
    const float* __restrict__ g, const float* __restrict__ b,
    float* __restrict__ outF, f16* __restrict__ outH) {
    const int row = blockIdx.x, t = threadIdx.x;
    const float4 xv = ((const float4*)(X + (size_t)row * 1024))[t];
    const float4 yv = ((const float4*)(Y + (size_t)row * 1024))[t];
    float v0 = xv.x + yv.x, v1 = xv.y + yv.y, v2 = xv.z + yv.z, v3 = xv.w + yv.w;
    __shared__ float red[8];
    float s = v0 + v1 + v2 + v3;
#pragma unroll
    for (int m = 1; m < 64; m <<= 1) s += __shfl_xor(s, m);
    if ((t & 63) == 0) red[t >> 6] = s;
    __syncthreads();
    float mu = (red[0] + red[1] + red[2] + red[3]) * (1.0f / 1024.0f);
    float d0 = v0 - mu, d1 = v1 - mu, d2 = v2 - mu, d3 = v3 - mu;
    float q = d0 * d0 + d1 * d1 + d2 * d2 + d3 * d3;
#pragma unroll
    for (int m = 1; m < 64; m <<= 1) q += __shfl_xor(q, m);
    if ((t & 63) == 0) red[4 + (t >> 6)] = q;
    __syncthreads();
    float var = (red[4] + red[5] + red[6] + red[7]) * (1.0f / 1024.0f);
    float rs = rsqrtf(var + 1e-5f);
    const float4 gv = ((const float4*)g)[t];
    const float4 bv = ((const float4*)b)[t];
    float o0 = d0 * rs * gv.x + bv.x;
    float o1 = d1 * rs * gv.y + bv.y;
    float o2 = d2 * rs * gv.z + bv.z;
    float o3 = d3 * rs * gv.w + bv.w;
    float4 ov = {o0, o1, o2, o3};
    ((float4*)(outF + (size_t)row * 1024))[t] = ov;
    if constexpr (WB) {
        f16x4 oh = {(f16)o0, (f16)o1, (f16)o2, (f16)o3};
        ((f16x4*)(outH + (size_t)row * 1024))[t] = oh;
    }
}

// ---------------------------------------------------------------- launch
extern "C" void kernel_launch(void* const* d_in, const int* in_sizes, int n_in,
                              void* d_out, int out_size, void* d_ws, size_t ws_size,
                              hipStream_t stream) {
    const float* x      = (const float*)d_in[0];
    const float* qkv_w  = (const float*)d_in[1];
    const float* qkv_b  = (const float*)d_in[2];
    const float* out_w  = (const float*)d_in[3];
    const float* out_b  = (const float*)d_in[4];
    const float* ln1_g  = (const float*)d_in[5];
    const float* ln1_b  = (const float*)d_in[6];
    const float* ln2_g  = (const float*)d_in[7];
    const float* ln2_b  = (const float*)d_in[8];
    const float* ffn1_w = (const float*)d_in[9];
    const float* ffn1_b = (const float*)d_in[10];
    const float* ffn2_w = (const float*)d_in[11];
    const float* ffn2_b = (const float*)d_in[12];
    float* out = (float*)d_out;
    char* ws = (char*)d_ws;

    constexpr size_t SZ_XB      = 4096ull * 1024 * 2;
    constexpr size_t SZ_QKV_WT  = 3072ull * 1024 * 2;
    constexpr size_t SZ_OUT_WT  = 1024ull * 1024 * 2;
    constexpr size_t SZ_FFN1_WT = 4096ull * 1024 * 2;
    constexpr size_t SZ_FFN2_WT = 1024ull * 4096 * 2;
    constexpr size_t SZ_CS      = 2048ull * 32 * 8;
    constexpr size_t SZ_X1F     = 4096ull * 1024 * 4;
    constexpr size_t SZ_X1H     = 4096ull * 1024 * 2;
    constexpr size_t SZ_FFN2O   = 4096ull * 1024 * 4;
    constexpr size_t SZ_QH      = 32ull * 2048 * 64 * 2;
    constexpr size_t SZ_REGB    = 4 * SZ_QH;
    constexpr size_t SZ_REGC    = 4096ull * 3072 * 2;

    size_t o = 0;
    auto take = [&](size_t sz) { size_t p = o; o += (sz + 255) & ~(size_t)255; return p; };
    const size_t O_XB      = take(SZ_XB);
    const size_t O_QKV_WT  = take(SZ_QKV_WT);
    const size_t O_OUT_WT  = take(SZ_OUT_WT);
    const size_t O_FFN1_WT = take(SZ_FFN1_WT);
    const size_t O_FFN2_WT = take(SZ_FFN2_WT);
    const size_t O_CS      = take(SZ_CS);
    const size_t O_X1F     = take(SZ_X1F);
    const size_t O_X1H     = take(SZ_X1H);
    const size_t O_FFN2O   = take(SZ_FFN2O);
    const size_t O_REGB    = take(SZ_REGB);
    const size_t O_REGC    = take(SZ_REGC);

    f16*    xb      = (f16*)(ws + O_XB);
    f16*    qkv_wt  = (f16*)(ws + O_QKV_WT);
    f16*    out_wt  = (f16*)(ws + O_OUT_WT);
    f16*    ffn1_wt = (f16*)(ws + O_FFN1_WT);
    f16*    ffn2_wt = (f16*)(ws + O_FFN2_WT);
    float2* cs      = (float2*)(ws + O_CS);
    float*  x1f     = (float*)(ws + O_X1F);
    f16*    x1h     = (f16*)(ws + O_X1H);
    float*  ffn2o   = (float*)(ws + O_FFN2O);
    f16*    Qb      = (f16*)(ws + O_REGB);
    f16*    Kb      = (f16*)(ws + O_REGB + SZ_QH);
    f16*    Vtb     = (f16*)(ws + O_REGB + 2 * SZ_QH);
    f16*    attn_o  = (f16*)(ws + O_REGB + 3 * SZ_QH);
    f16*    hbuf    = (f16*)(ws + O_REGB);
    f16*    qkvo    = (f16*)(ws + O_REGC);
    float*  proj    = (float*)(ws + O_REGC);

    cast_f16_kernel<<<4096, 256, 0, stream>>>(x, xb, 4096 * 1024 / 4);
    transpose_cast_kernel<<<dim3(96, 32), 256, 0, stream>>>(qkv_w, qkv_wt, 1024, 3072);
    transpose_cast_kernel<<<dim3(32, 32), 256, 0, stream>>>(out_w, out_wt, 1024, 1024);
    transpose_cast_kernel<<<dim3(128, 32), 256, 0, stream>>>(ffn1_w, ffn1_wt, 1024, 4096);
    transpose_cast_kernel<<<dim3(32, 128), 256, 0, stream>>>(ffn2_w, ffn2_wt, 4096, 1024);
    rope_table_kernel<<<256, 256, 0, stream>>>(cs);

    gemm_bt<EPI_NONE, f16><<<32 * 24, 256, 0, stream>>>(xb, qkv_wt, qkv_b, qkvo, 4096, 3072, 1024);
    rope_pack_kernel<<<1024, 256, 0, stream>>>(qkvo, cs, Qb, Kb, Vtb);
    attn_fwd<<<256, 512, 0, stream>>>(Qb, Kb, Vtb, attn_o);
    gemm_bt<EPI_NONE, float><<<32 * 8, 256, 0, stream>>>(attn_o, out_wt, out_b, proj, 4096, 1024, 1024);
    ln_fused<true><<<4096, 256, 0, stream>>>(x, proj, ln1_g, ln1_b, x1f, x1h);
    gemm_bt<EPI_GELU, f16><<<32 * 32, 256, 0, stream>>>(x1h, ffn1_wt, ffn1_b, hbuf, 4096, 4096, 1024);
    gemm_bt<EPI_NONE, float><<<32 * 8, 256, 0, stream>>>(hbuf, ffn2_wt, ffn2_b, ffn2o, 4096, 1024, 4096);
    ln_fused<false><<<4096, 256, 0, stream>>>(x1f, ffn2o, ln2_g, ln2_b, out, nullptr);
}